// Round 17
// baseline (324.930 us; speedup 1.0000x reference)
//
#include <hip/hip_runtime.h>
#include <hip/hip_bf16.h>
#include <math.h>

#define D_MODEL 1024
#define D_HID   4096
#define NE      8
#define NTOK    4096
#define NSLOT   8192

typedef __attribute__((ext_vector_type(8))) short s8v;
typedef __attribute__((ext_vector_type(4))) float f32x4;

__device__ __forceinline__ short f2bf(float f) {
    unsigned u = __float_as_uint(f);
    unsigned r = (u + 0x7fffu + ((u >> 16) & 1u)) >> 16;
    return (short)r;
}

__device__ __forceinline__ float bf2f(short s) {
    unsigned u = ((unsigned)(unsigned short)s) << 16;
    return __uint_as_float(u);
}

__device__ __forceinline__ void load_lds16(const short* g, short* l) {
    __builtin_amdgcn_global_load_lds(
        (const __attribute__((address_space(1))) void*)g,
        (__attribute__((address_space(3))) void*)l, 16, 0, 0);
}

// tanh-GELU (max abs err ~3e-4 — far under the bf16 floor we already carry)
__device__ __forceinline__ float gelu_t(float v) {
    float u = v * fmaf(0.0356774081f, v * v, 0.7978845608f);
    float e = __expf(-2.0f * u);
    return v * __builtin_amdgcn_rcpf(1.0f + e);
}

// ---------------- fused x-convert + router ----------------

__global__ void k_cvt_router(const float* __restrict__ x, const float* __restrict__ gw,
                             short* __restrict__ xb,
                             int* __restrict__ tki, float* __restrict__ tkw) {
    int n = blockIdx.x;
    int lane = threadIdx.x;
    const float4* x4 = (const float4*)x;
    const float4* g4 = (const float4*)gw;
    float4 xv[4];
    #pragma unroll
    for (int j = 0; j < 4; j++) xv[j] = x4[(size_t)n * 256 + lane + 64 * j];
    #pragma unroll
    for (int j = 0; j < 4; j++) {
        short4 o;
        o.x = f2bf(xv[j].x); o.y = f2bf(xv[j].y);
        o.z = f2bf(xv[j].z); o.w = f2bf(xv[j].w);
        *(short4*)(xb + (size_t)n * D_MODEL + 4 * (lane + 64 * j)) = o;
    }
    float l[8];
    #pragma unroll
    for (int e = 0; e < 8; e++) {
        float a = 0.f;
        #pragma unroll
        for (int j = 0; j < 4; j++) {
            float4 g = g4[e * 256 + lane + 64 * j];
            a = fmaf(xv[j].x, g.x, a);
            a = fmaf(xv[j].y, g.y, a);
            a = fmaf(xv[j].z, g.z, a);
            a = fmaf(xv[j].w, g.w, a);
        }
        #pragma unroll
        for (int s = 32; s > 0; s >>= 1) a += __shfl_xor(a, s);
        l[e] = a;
    }
    if (lane == 0) {
        float bv = -1e30f, sv = -1e30f; int bi = 0, si = 0;
        #pragma unroll
        for (int e = 0; e < 8; e++) {
            float v = l[e];
            if (v > bv) { sv = bv; si = bi; bv = v; bi = e; }
            else if (v > sv) { sv = v; si = e; }
        }
        float w0 = 1.f / (1.f + expf(sv - bv));
        tki[n * 2] = bi; tki[n * 2 + 1] = si;
        tkw[n * 2] = w0; tkw[n * 2 + 1] = 1.f - w0;
    }
}

// ---------------- weight transposes (merged) ----------------

__global__ void k_transpose_cvt2(const float* __restrict__ w1, const float* __restrict__ w2,
                                 short* __restrict__ w1t, short* __restrict__ w2t) {
    __shared__ float tile[64][65];
    int z = blockIdx.z;
    int R, C;
    const float* inp;
    short* outp;
    int tIdx = blockIdx.y * 64 + blockIdx.x;
    if (z < 8) {
        R = D_MODEL; C = D_HID;
        inp  = w1  + (size_t)z * R * C;
        outp = w1t + (size_t)z * R * C;
    } else {
        R = D_HID; C = D_MODEL;
        inp  = w2  + (size_t)(z - 8) * R * C;
        outp = w2t + (size_t)(z - 8) * R * C;
    }
    int tilesC = C >> 6;
    int c0 = (tIdx % tilesC) * 64;
    int r0 = (tIdx / tilesC) * 64;
    int t = threadIdx.x;
    #pragma unroll
    for (int p = 0; p < 4; p++) {
        int idx = p * 256 + t;
        int r = idx >> 4;
        int c4 = (idx & 15) * 4;
        float4 v = *(const float4*)(inp + (size_t)(r0 + r) * C + c0 + c4);
        tile[r][c4 + 0] = v.x; tile[r][c4 + 1] = v.y;
        tile[r][c4 + 2] = v.z; tile[r][c4 + 3] = v.w;
    }
    __syncthreads();
    #pragma unroll
    for (int p = 0; p < 4; p++) {
        int idx = p * 256 + t;
        int cc = idx >> 4;
        int rg = (idx & 15) * 4;
        short4 v;
        v.x = f2bf(tile[rg + 0][cc]);
        v.y = f2bf(tile[rg + 1][cc]);
        v.z = f2bf(tile[rg + 2][cc]);
        v.w = f2bf(tile[rg + 3][cc]);
        *(short4*)(outp + (size_t)(c0 + cc) * R + r0 + rg) = v;
    }
}

// ---------------- bucketing: count + scan + fill in ONE single-block kernel ----------------

__global__ __launch_bounds__(1024) void k_bucket(
    const int* __restrict__ tki, const float* __restrict__ tkw,
    int* __restrict__ offs,
    int* __restrict__ list, float* __restrict__ wl, int* __restrict__ slot_of) {
    __shared__ int cnt[NE], base[NE + 1], fil[NE];
    int t = threadIdx.x;
    if (t < NE) { cnt[t] = 0; fil[t] = 0; }
    __syncthreads();
    for (int n = t; n < NTOK; n += 1024) {
        atomicAdd(&cnt[tki[n * 2]], 1);
        atomicAdd(&cnt[tki[n * 2 + 1]], 1);
    }
    __syncthreads();
    if (t == 0) {
        int a = 0;
        for (int e = 0; e < NE; e++) { base[e] = a; a += cnt[e]; }
        base[NE] = a;
    }
    __syncthreads();
    if (t < NE + 1) offs[t] = base[t];
    for (int n = t; n < NTOK; n += 1024) {
        #pragma unroll
        for (int k = 0; k < 2; k++) {
            int e = tki[n * 2 + k];
            int p = base[e] + atomicAdd(&fil[e], 1);
            list[p] = n;
            wl[p] = tkw[n * 2 + k];
            slot_of[n * 2 + k] = p;
        }
    }
}

// ---------------- shared pipeline macros ----------------

#define PIPE_WAIT(NSTR) \
    asm volatile("s_waitcnt vmcnt(" NSTR ")" ::: "memory"); \
    __builtin_amdgcn_s_barrier(); \
    __builtin_amdgcn_sched_barrier(0);

#define PIPE_POST \
    asm volatile("" ::: "memory"); \
    __builtin_amdgcn_s_barrier();

#define GEMM_PIPE_LOOP(KDIM, STAGE, COMPUTE, NSTR) \
    STAGE(As0, Bs0); \
    for (int k0 = 0; k0 < (KDIM) - 128; k0 += 128) { \
        STAGE(As1, Bs1); PIPE_WAIT(NSTR) COMPUTE(As0, Bs0) PIPE_POST \
        STAGE(As0, Bs0); PIPE_WAIT(NSTR) COMPUTE(As1, Bs1) PIPE_POST \
    } \
    STAGE(As1, Bs1); PIPE_WAIT(NSTR) COMPUTE(As0, Bs0) PIPE_POST \
    PIPE_WAIT("0") COMPUTE(As1, Bs1)

// ---------------- 64(M)x128(N) tile machinery (round-12/13-verified) ----------------
// STAGE = 2 A-loads + 4 B-loads = 6 -> vmcnt(6) waits exactly on prev stage.

#define STAGE_T(ABASE, BBASE) \
    { _Pragma("unroll") \
      for (int c = 0; c < 2; c++) { load_lds16(aS[c], (ABASE) + ldsDa[c]); aS[c] += 64; } \
      _Pragma("unroll") \
      for (int c = 0; c < 4; c++) { load_lds16(bS[c], (BBASE) + ldsDb[c]); bS[c] += 64; } }

#define COMPUTE_T(ABASE, BBASE) \
    { _Pragma("unroll") \
      for (int kk = 0; kk < 2; kk++) { \
          s8v a[2], b[4]; \
          _Pragma("unroll") \
          for (int i = 0; i < 2; i++) a[i] = *(const s8v*)((ABASE) + aO[i][kk]); \
          _Pragma("unroll") \
          for (int j = 0; j < 4; j++) b[j] = *(const s8v*)((BBASE) + bO[j][kk]); \
          _Pragma("unroll") \
          for (int i = 0; i < 2; i++) \
              _Pragma("unroll") \
              for (int j = 0; j < 4; j++) \
                  acc[i][j] = __builtin_amdgcn_mfma_f32_16x16x32_bf16(a[i], b[j], acc[i][j], 0, 0, 0); \
      } }

#define FRAG_SETUP_T \
    int tid = threadIdx.x; \
    int lane = tid & 63; \
    int wid = tid >> 6; \
    int wm = wid >> 1, wn = wid & 1; \
    f32x4 acc[2][4] = {}; \
    int aO[2][2], bO[4][2]; \
    _Pragma("unroll") \
    for (int k = 0; k < 2; k++) { \
        int l = k * 4 + (lane >> 4); \
        _Pragma("unroll") \
        for (int i = 0; i < 2; i++) { \
            int R = wm * 32 + i * 16 + (lane & 15); \
            aO[i][k] = R * 64 + ((l ^ (R & 7)) * 8); \
        } \
        _Pragma("unroll") \
        for (int j = 0; j < 4; j++) { \
            int R = wn * 64 + j * 16 + (lane & 15); \
            bO[j][k] = R * 64 + ((l ^ (R & 7)) * 8); \
        } \
    }

// ---------------- GEMM 1: 64x128, CHUNKED map + counted-dbuf ----------------
// Round-16 chunked decode byte-identical (FETCH 103 MB measured); only the
// loop changes: single-buf -> 2-buf counted vmcnt (verified at this tile in
// gemm2 since round 13). Isolates dbuf-with-order-driven-locality.

__global__ __launch_bounds__(256) void k_gemm1(
    const short* __restrict__ xb,      // [NTOK][D_MODEL] bf16
    const short* __restrict__ w1t,     // [E][D_HID][D_MODEL] bf16
    const float* __restrict__ b1,
    const int* __restrict__ offs,
    const int* __restrict__ list,
    short* __restrict__ hbuf)          // [NSLOT][D_HID] bf16
{
    int id = blockIdx.x;
    int w = (id & 7) * 2048 + (id >> 3);
    int e = w >> 11;
    int o0 = offs[e];
    int nE = offs[e + 1] - o0;
    int local = w & 2047;
    int intra = local & 63;
    int chunk = local >> 6;            // 32 chunks of 64 blocks (8n x 8m)
    int n0 = ((chunk & 3) * 8 + (intra & 7)) * 128;
    int m0 = ((chunk >> 2) * 8 + (intra >> 3)) * 64;
    if (m0 >= nE) return;

    __shared__ short As0[64 * 64], Bs0[128 * 64];
    __shared__ short As1[64 * 64], Bs1[128 * 64];

    FRAG_SETUP_T

    const short* aS[2]; const short* bS[4];
    int ldsDa[2], ldsDb[4];
    #pragma unroll
    for (int c = 0; c < 2; c++) {
        int i = c * 256 + tid;                   // 0..511
        int rowT = i >> 3, s = i & 7;
        int ch = s ^ (rowT & 7);                 // pre-swizzled source chunk
        int r = m0 + rowT; if (r > nE - 1) r = nE - 1;
        int tok = list[o0 + r];
        aS[c] = xb + (size_t)tok * D_MODEL + ch * 8;
        ldsDa[c] = i * 8;
    }
    #pragma unroll
    for (int c = 0; c < 4; c++) {
        int i = c * 256 + tid;                   // 0..1023
        int rowT = i >> 3, s = i & 7;
        int ch = s ^ (rowT & 7);
        bS[c] = w1t + ((size_t)e * D_HID + n0 + rowT) * D_MODEL + ch * 8;
        ldsDb[c] = i * 8;
    }

    GEMM_PIPE_LOOP(D_MODEL, STAGE_T, COMPUTE_T, "6")

    int rBase = m0 + wm * 32 + (lane >> 4) * 4;
    int cBase = n0 + wn * 64 + (lane & 15);
    #pragma unroll
    for (int i = 0; i < 2; i++) {
        #pragma unroll
        for (int j = 0; j < 4; j++) {
            int cc = cBase + j * 16;
            float bias = b1[e * D_HID + cc];
            #pragma unroll
            for (int rg = 0; rg < 4; rg++) {
                int rr = rBase + i * 16 + rg;
                if (rr < nE) {
                    float v = acc[i][j][rg] + bias;
                    hbuf[(size_t)(o0 + rr) * D_HID + cc] = f2bf(gelu_t(v));
                }
            }
        }
    }
}

// ---------------- GEMM 2: 64x128, 2-buf counted + TLP (round-13 exact) ----------------

__global__ __launch_bounds__(256) void k_gemm2(
    const short* __restrict__ hbuf,    // [NSLOT][D_HID] bf16
    const short* __restrict__ w2t,     // [E][D_MODEL][D_HID] bf16
    const float* __restrict__ b2,
    const int* __restrict__ offs,
    const float* __restrict__ wl,
    short* __restrict__ ybuf)          // [NSLOT][D_MODEL] bf16
{
    int id = blockIdx.x;
    int w = (id & 7) * 512 + (id >> 3);
    int e = w >> 9;
    int o0 = offs[e];
    int nE = offs[e + 1] - o0;
    int m0 = ((w >> 3) & 63) * 64;
    if (m0 >= nE) return;
    int n0 = (w & 7) * 128;

    __shared__ short As0[64 * 64], Bs0[128 * 64];
    __shared__ short As1[64 * 64], Bs1[128 * 64];

    FRAG_SETUP_T

    const short* aS[2]; const short* bS[4];
    int ldsDa[2], ldsDb[4];
    #pragma unroll
    for (int c = 0; c < 2; c++) {
        int i = c * 256 + tid;
        int rowT = i >> 3, s = i & 7;
        int ch = s ^ (rowT & 7);
        int r = m0 + rowT; if (r > nE - 1) r = nE - 1;
        aS[c] = hbuf + (size_t)(o0 + r) * D_HID + ch * 8;
        ldsDa[c] = i * 8;
    }
    #pragma unroll
    for (int c = 0; c < 4; c++) {
        int i = c * 256 + tid;
        int rowT = i >> 3, s = i & 7;
        int ch = s ^ (rowT & 7);
        bS[c] = w2t + ((size_t)e * D_MODEL + n0 + rowT) * D_HID + ch * 8;
        ldsDb[c] = i * 8;
    }

    GEMM_PIPE_LOOP(D_HID, STAGE_T, COMPUTE_T, "6")

    int rBase = m0 + wm * 32 + (lane >> 4) * 4;
    int cBase = n0 + wn * 64 + (lane & 15);
    #pragma unroll
    for (int i = 0; i < 2; i++) {
        #pragma unroll
        for (int j = 0; j < 4; j++) {
            int cc = cBase + j * 16;
            float bias = b2[e * D_MODEL + cc];
            #pragma unroll
            for (int rg = 0; rg < 4; rg++) {
                int rr = rBase + i * 16 + rg;
                if (rr < nE) {
                    int slot = o0 + rr;
                    float wgt = wl[slot];
                    ybuf[(size_t)slot * D_MODEL + cc] = f2bf(wgt * (acc[i][j][rg] + bias));
                }
            }
        }
    }
}

// ---------------- combine (bf16 ybuf -> fp32 out) ----------------

__global__ void k_combine(const short* __restrict__ ybuf, const int* __restrict__ slot_of,
                          float* __restrict__ out) {
    int n = blockIdx.x;
    int s0 = slot_of[n * 2], s1 = slot_of[n * 2 + 1];
    int t = threadIdx.x;
    short4 a = *(const short4*)(ybuf + (size_t)s0 * D_MODEL + t * 4);
    short4 b = *(const short4*)(ybuf + (size_t)s1 * D_MODEL + t * 4);
    float4 o;
    o.x = bf2f(a.x) + bf2f(b.x);
    o.y = bf2f(a.y) + bf2f(b.y);
    o.z = bf2f(a.z) + bf2f(b.z);
    o.w = bf2f(a.w) + bf2f(b.w);
    *(float4*)(out + (size_t)n * D_MODEL + t * 4) = o;
}

// ---------------- launch ----------------

extern "C" void kernel_launch(void* const* d_in, const int* in_sizes, int n_in,
                              void* d_out, int out_size, void* d_ws, size_t ws_size,
                              hipStream_t stream) {
    const float* x  = (const float*)d_in[0];
    const float* gw = (const float*)d_in[1];
    const float* w1 = (const float*)d_in[2];
    const float* b1 = (const float*)d_in[3];
    const float* w2 = (const float*)d_in[4];
    const float* b2 = (const float*)d_in[5];
    float* out = (float*)d_out;

    char* ws = (char*)d_ws;
    size_t off = 0;
    auto alloc = [&](size_t bytes) -> void* {
        void* p = ws + off;
        off += (bytes + 255) & ~(size_t)255;
        return p;
    };
    int*   offs    = (int*)alloc(64);
    int*   tki     = (int*)alloc((size_t)NTOK * 2 * 4);
    float* tkw     = (float*)alloc((size_t)NTOK * 2 * 4);
    int*   list    = (int*)alloc((size_t)NSLOT * 4);
    float* wl      = (float*)alloc((size_t)NSLOT * 4);
    int*   slot_of = (int*)alloc((size_t)NTOK * 2 * 4);
    short* xb      = (short*)alloc((size_t)NTOK * D_MODEL * 2);
    short* w1t     = (short*)alloc((size_t)NE * D_HID * D_MODEL * 2);
    short* w2t     = (short*)alloc((size_t)NE * D_MODEL * D_HID * 2);
    short* hbuf    = (short*)alloc((size_t)NSLOT * D_HID * 2);
    short* ybuf    = (short*)alloc((size_t)NSLOT * D_MODEL * 2);

    k_cvt_router<<<dim3(NTOK), 64, 0, stream>>>(x, gw, xb, tki, tkw);
    k_transpose_cvt2<<<dim3(64, 16, 16), 256, 0, stream>>>(w1, w2, w1t, w2t);
    k_bucket<<<dim3(1), 1024, 0, stream>>>(tki, tkw, offs, list, wl, slot_of);
    k_gemm1<<<dim3(16384), 256, 0, stream>>>(xb, w1t, b1, offs, list, hbuf);
    k_gemm2<<<dim3(4096), 256, 0, stream>>>(hbuf, w2t, b2, offs, wl, ybuf);
    k_combine<<<dim3(NTOK), 256, 0, stream>>>(ybuf, slot_of, out);
}

// Round 18
// 318.919 us; speedup vs baseline: 1.0188x; 1.0188x over previous
//
#include <hip/hip_runtime.h>
#include <hip/hip_bf16.h>
#include <math.h>

#define D_MODEL 1024
#define D_HID   4096
#define NE      8
#define NTOK    4096
#define NSLOT   8192

typedef __attribute__((ext_vector_type(8))) short s8v;
typedef __attribute__((ext_vector_type(4))) float f32x4;

__device__ __forceinline__ short f2bf(float f) {
    unsigned u = __float_as_uint(f);
    unsigned r = (u + 0x7fffu + ((u >> 16) & 1u)) >> 16;
    return (short)r;
}

__device__ __forceinline__ float bf2f(short s) {
    unsigned u = ((unsigned)(unsigned short)s) << 16;
    return __uint_as_float(u);
}

__device__ __forceinline__ void load_lds16(const short* g, short* l) {
    __builtin_amdgcn_global_load_lds(
        (const __attribute__((address_space(1))) void*)g,
        (__attribute__((address_space(3))) void*)l, 16, 0, 0);
}

// tanh-GELU (max abs err ~3e-4 — far under the bf16 floor we already carry)
__device__ __forceinline__ float gelu_t(float v) {
    float u = v * fmaf(0.0356774081f, v * v, 0.7978845608f);
    float e = __expf(-2.0f * u);
    return v * __builtin_amdgcn_rcpf(1.0f + e);
}

// ---------------- fused x-convert + router (256 thr, 1 wave per token) ----------------

__global__ __launch_bounds__(256) void k_cvt_router(
    const float* __restrict__ x, const float* __restrict__ gw,
    short* __restrict__ xb,
    int* __restrict__ tki, float* __restrict__ tkw) {
    int n = blockIdx.x * 4 + (threadIdx.x >> 6);
    int lane = threadIdx.x & 63;
    const float4* x4 = (const float4*)x;
    const float4* g4 = (const float4*)gw;
    float4 xv[4];
    #pragma unroll
    for (int j = 0; j < 4; j++) xv[j] = x4[(size_t)n * 256 + lane + 64 * j];
    #pragma unroll
    for (int j = 0; j < 4; j++) {
        short4 o;
        o.x = f2bf(xv[j].x); o.y = f2bf(xv[j].y);
        o.z = f2bf(xv[j].z); o.w = f2bf(xv[j].w);
        *(short4*)(xb + (size_t)n * D_MODEL + 4 * (lane + 64 * j)) = o;
    }
    float l[8];
    #pragma unroll
    for (int e = 0; e < 8; e++) {
        float a = 0.f;
        #pragma unroll
        for (int j = 0; j < 4; j++) {
            float4 g = g4[e * 256 + lane + 64 * j];
            a = fmaf(xv[j].x, g.x, a);
            a = fmaf(xv[j].y, g.y, a);
            a = fmaf(xv[j].z, g.z, a);
            a = fmaf(xv[j].w, g.w, a);
        }
        #pragma unroll
        for (int s = 32; s > 0; s >>= 1) a += __shfl_xor(a, s);
        l[e] = a;
    }
    if (lane == 0) {
        float bv = -1e30f, sv = -1e30f; int bi = 0, si = 0;
        #pragma unroll
        for (int e = 0; e < 8; e++) {
            float v = l[e];
            if (v > bv) { sv = bv; si = bi; bv = v; bi = e; }
            else if (v > sv) { sv = v; si = e; }
        }
        float w0 = 1.f / (1.f + expf(sv - bv));
        tki[n * 2] = bi; tki[n * 2 + 1] = si;
        tkw[n * 2] = w0; tkw[n * 2 + 1] = 1.f - w0;
    }
}

// ---------------- weight transposes (merged) ----------------

__global__ void k_transpose_cvt2(const float* __restrict__ w1, const float* __restrict__ w2,
                                 short* __restrict__ w1t, short* __restrict__ w2t) {
    __shared__ float tile[64][65];
    int z = blockIdx.z;
    int R, C;
    const float* inp;
    short* outp;
    int tIdx = blockIdx.y * 64 + blockIdx.x;
    if (z < 8) {
        R = D_MODEL; C = D_HID;
        inp  = w1  + (size_t)z * R * C;
        outp = w1t + (size_t)z * R * C;
    } else {
        R = D_HID; C = D_MODEL;
        inp  = w2  + (size_t)(z - 8) * R * C;
        outp = w2t + (size_t)(z - 8) * R * C;
    }
    int tilesC = C >> 6;
    int c0 = (tIdx % tilesC) * 64;
    int r0 = (tIdx / tilesC) * 64;
    int t = threadIdx.x;
    #pragma unroll
    for (int p = 0; p < 4; p++) {
        int idx = p * 256 + t;
        int r = idx >> 4;
        int c4 = (idx & 15) * 4;
        float4 v = *(const float4*)(inp + (size_t)(r0 + r) * C + c0 + c4);
        tile[r][c4 + 0] = v.x; tile[r][c4 + 1] = v.y;
        tile[r][c4 + 2] = v.z; tile[r][c4 + 3] = v.w;
    }
    __syncthreads();
    #pragma unroll
    for (int p = 0; p < 4; p++) {
        int idx = p * 256 + t;
        int cc = idx >> 4;
        int rg = (idx & 15) * 4;
        short4 v;
        v.x = f2bf(tile[rg + 0][cc]);
        v.y = f2bf(tile[rg + 1][cc]);
        v.z = f2bf(tile[rg + 2][cc]);
        v.w = f2bf(tile[rg + 3][cc]);
        *(short4*)(outp + (size_t)(c0 + cc) * R + r0 + rg) = v;
    }
}

// ---------------- bucketing: count + scan + fill in ONE single-block kernel ----------------

__global__ __launch_bounds__(1024) void k_bucket(
    const int* __restrict__ tki, const float* __restrict__ tkw,
    int* __restrict__ offs,
    int* __restrict__ list, float* __restrict__ wl, int* __restrict__ slot_of) {
    __shared__ int cnt[NE], base[NE + 1], fil[NE];
    int t = threadIdx.x;
    if (t < NE) { cnt[t] = 0; fil[t] = 0; }
    __syncthreads();
    for (int n = t; n < NTOK; n += 1024) {
        atomicAdd(&cnt[tki[n * 2]], 1);
        atomicAdd(&cnt[tki[n * 2 + 1]], 1);
    }
    __syncthreads();
    if (t == 0) {
        int a = 0;
        for (int e = 0; e < NE; e++) { base[e] = a; a += cnt[e]; }
        base[NE] = a;
    }
    __syncthreads();
    if (t < NE + 1) offs[t] = base[t];
    for (int n = t; n < NTOK; n += 1024) {
        #pragma unroll
        for (int k = 0; k < 2; k++) {
            int e = tki[n * 2 + k];
            int p = base[e] + atomicAdd(&fil[e], 1);
            list[p] = n;
            wl[p] = tkw[n * 2 + k];
            slot_of[n * 2 + k] = p;
        }
    }
}

// ---------------- shared pipeline macros ----------------

#define PIPE_WAIT(NSTR) \
    asm volatile("s_waitcnt vmcnt(" NSTR ")" ::: "memory"); \
    __builtin_amdgcn_s_barrier(); \
    __builtin_amdgcn_sched_barrier(0);

#define PIPE_POST \
    asm volatile("" ::: "memory"); \
    __builtin_amdgcn_s_barrier();

#define GEMM_PIPE_LOOP(KDIM, STAGE, COMPUTE, NSTR) \
    STAGE(As0, Bs0); \
    for (int k0 = 0; k0 < (KDIM) - 128; k0 += 128) { \
        STAGE(As1, Bs1); PIPE_WAIT(NSTR) COMPUTE(As0, Bs0) PIPE_POST \
        STAGE(As0, Bs0); PIPE_WAIT(NSTR) COMPUTE(As1, Bs1) PIPE_POST \
    } \
    STAGE(As1, Bs1); PIPE_WAIT(NSTR) COMPUTE(As0, Bs0) PIPE_POST \
    PIPE_WAIT("0") COMPUTE(As1, Bs1)

// ---------------- 64(M)x128(N) tile machinery (round-12/13-verified) ----------------

#define STAGE_T(ABASE, BBASE) \
    { _Pragma("unroll") \
      for (int c = 0; c < 2; c++) { load_lds16(aS[c], (ABASE) + ldsDa[c]); aS[c] += 64; } \
      _Pragma("unroll") \
      for (int c = 0; c < 4; c++) { load_lds16(bS[c], (BBASE) + ldsDb[c]); bS[c] += 64; } }

#define COMPUTE_T(ABASE, BBASE) \
    { _Pragma("unroll") \
      for (int kk = 0; kk < 2; kk++) { \
          s8v a[2], b[4]; \
          _Pragma("unroll") \
          for (int i = 0; i < 2; i++) a[i] = *(const s8v*)((ABASE) + aO[i][kk]); \
          _Pragma("unroll") \
          for (int j = 0; j < 4; j++) b[j] = *(const s8v*)((BBASE) + bO[j][kk]); \
          _Pragma("unroll") \
          for (int i = 0; i < 2; i++) \
              _Pragma("unroll") \
              for (int j = 0; j < 4; j++) \
                  acc[i][j] = __builtin_amdgcn_mfma_f32_16x16x32_bf16(a[i], b[j], acc[i][j], 0, 0, 0); \
      } }

#define FRAG_SETUP_T \
    int tid = threadIdx.x; \
    int lane = tid & 63; \
    int wid = tid >> 6; \
    int wm = wid >> 1, wn = wid & 1; \
    f32x4 acc[2][4] = {}; \
    int aO[2][2], bO[4][2]; \
    _Pragma("unroll") \
    for (int k = 0; k < 2; k++) { \
        int l = k * 4 + (lane >> 4); \
        _Pragma("unroll") \
        for (int i = 0; i < 2; i++) { \
            int R = wm * 32 + i * 16 + (lane & 15); \
            aO[i][k] = R * 64 + ((l ^ (R & 7)) * 8); \
        } \
        _Pragma("unroll") \
        for (int j = 0; j < 4; j++) { \
            int R = wn * 64 + j * 16 + (lane & 15); \
            bO[j][k] = R * 64 + ((l ^ (R & 7)) * 8); \
        } \
    }

// ---------------- GEMM 1: 64x128 single-buffer TLP + CHUNKED map (round-16 EXACT) ----------------

__global__ __launch_bounds__(256) void k_gemm1(
    const short* __restrict__ xb,      // [NTOK][D_MODEL] bf16
    const short* __restrict__ w1t,     // [E][D_HID][D_MODEL] bf16
    const float* __restrict__ b1,
    const int* __restrict__ offs,
    const int* __restrict__ list,
    short* __restrict__ hbuf)          // [NSLOT][D_HID] bf16
{
    int id = blockIdx.x;
    int w = (id & 7) * 2048 + (id >> 3);
    int e = w >> 11;
    int o0 = offs[e];
    int nE = offs[e + 1] - o0;
    int local = w & 2047;
    int intra = local & 63;
    int chunk = local >> 6;            // 32 chunks of 64 blocks (8n x 8m)
    int n0 = ((chunk & 3) * 8 + (intra & 7)) * 128;
    int m0 = ((chunk >> 2) * 8 + (intra >> 3)) * 64;
    if (m0 >= nE) return;

    __shared__ short As[64 * 64];      // 8 KB
    __shared__ short Bs[128 * 64];     // 16 KB

    int tid = threadIdx.x;
    int lane = tid & 63;
    int wid = tid >> 6;
    int wm = wid >> 1, wn = wid & 1;   // wave tile 32(M) x 64(N)

    f32x4 acc[2][4] = {};

    const short* aS[2]; const short* bS[4];
    int ldsDa[2], ldsDb[4];
    #pragma unroll
    for (int c = 0; c < 2; c++) {
        int i = c * 256 + tid;                   // 0..511
        int rowT = i >> 3, s = i & 7;
        int ch = s ^ (rowT & 7);                 // pre-swizzled source chunk
        int r = m0 + rowT; if (r > nE - 1) r = nE - 1;
        int tok = list[o0 + r];
        aS[c] = xb + (size_t)tok * D_MODEL + ch * 8;
        ldsDa[c] = i * 8;
    }
    #pragma unroll
    for (int c = 0; c < 4; c++) {
        int i = c * 256 + tid;                   // 0..1023
        int rowT = i >> 3, s = i & 7;
        int ch = s ^ (rowT & 7);
        bS[c] = w1t + ((size_t)e * D_HID + n0 + rowT) * D_MODEL + ch * 8;
        ldsDb[c] = i * 8;
    }

    int aO[2][2], bO[4][2];
    #pragma unroll
    for (int k = 0; k < 2; k++) {
        int l = k * 4 + (lane >> 4);
        #pragma unroll
        for (int i = 0; i < 2; i++) {
            int R = wm * 32 + i * 16 + (lane & 15);
            aO[i][k] = R * 64 + ((l ^ (R & 7)) * 8);
        }
        #pragma unroll
        for (int j = 0; j < 4; j++) {
            int R = wn * 64 + j * 16 + (lane & 15);
            bO[j][k] = R * 64 + ((l ^ (R & 7)) * 8);
        }
    }

    for (int k0 = 0; k0 < D_MODEL; k0 += 64) {
        __syncthreads();
        #pragma unroll
        for (int c = 0; c < 2; c++) { load_lds16(aS[c], As + ldsDa[c]); aS[c] += 64; }
        #pragma unroll
        for (int c = 0; c < 4; c++) { load_lds16(bS[c], Bs + ldsDb[c]); bS[c] += 64; }
        asm volatile("s_waitcnt vmcnt(0)" ::: "memory");
        __syncthreads();
        #pragma unroll
        for (int kk = 0; kk < 2; kk++) {
            s8v a[2], b[4];
            #pragma unroll
            for (int i = 0; i < 2; i++) a[i] = *(const s8v*)(As + aO[i][kk]);
            #pragma unroll
            for (int j = 0; j < 4; j++) b[j] = *(const s8v*)(Bs + bO[j][kk]);
            #pragma unroll
            for (int i = 0; i < 2; i++)
                #pragma unroll
                for (int j = 0; j < 4; j++)
                    acc[i][j] = __builtin_amdgcn_mfma_f32_16x16x32_bf16(a[i], b[j], acc[i][j], 0, 0, 0);
        }
    }

    int rBase = m0 + wm * 32 + (lane >> 4) * 4;
    int cBase = n0 + wn * 64 + (lane & 15);
    #pragma unroll
    for (int i = 0; i < 2; i++) {
        #pragma unroll
        for (int j = 0; j < 4; j++) {
            int cc = cBase + j * 16;
            float bias = b1[e * D_HID + cc];
            #pragma unroll
            for (int rg = 0; rg < 4; rg++) {
                int rr = rBase + i * 16 + rg;
                if (rr < nE) {
                    float v = acc[i][j][rg] + bias;
                    hbuf[(size_t)(o0 + rr) * D_HID + cc] = f2bf(gelu_t(v));
                }
            }
        }
    }
}

// ---------------- GEMM 2: 64x128, 2-buf counted + TLP (round-13 exact) ----------------

__global__ __launch_bounds__(256) void k_gemm2(
    const short* __restrict__ hbuf,    // [NSLOT][D_HID] bf16
    const short* __restrict__ w2t,     // [E][D_MODEL][D_HID] bf16
    const float* __restrict__ b2,
    const int* __restrict__ offs,
    const float* __restrict__ wl,
    short* __restrict__ ybuf)          // [NSLOT][D_MODEL] bf16
{
    int id = blockIdx.x;
    int w = (id & 7) * 512 + (id >> 3);
    int e = w >> 9;
    int o0 = offs[e];
    int nE = offs[e + 1] - o0;
    int m0 = ((w >> 3) & 63) * 64;
    if (m0 >= nE) return;
    int n0 = (w & 7) * 128;

    __shared__ short As0[64 * 64], Bs0[128 * 64];
    __shared__ short As1[64 * 64], Bs1[128 * 64];

    FRAG_SETUP_T

    const short* aS[2]; const short* bS[4];
    int ldsDa[2], ldsDb[4];
    #pragma unroll
    for (int c = 0; c < 2; c++) {
        int i = c * 256 + tid;
        int rowT = i >> 3, s = i & 7;
        int ch = s ^ (rowT & 7);
        int r = m0 + rowT; if (r > nE - 1) r = nE - 1;
        aS[c] = hbuf + (size_t)(o0 + r) * D_HID + ch * 8;
        ldsDa[c] = i * 8;
    }
    #pragma unroll
    for (int c = 0; c < 4; c++) {
        int i = c * 256 + tid;
        int rowT = i >> 3, s = i & 7;
        int ch = s ^ (rowT & 7);
        bS[c] = w2t + ((size_t)e * D_MODEL + n0 + rowT) * D_HID + ch * 8;
        ldsDb[c] = i * 8;
    }

    GEMM_PIPE_LOOP(D_HID, STAGE_T, COMPUTE_T, "6")

    int rBase = m0 + wm * 32 + (lane >> 4) * 4;
    int cBase = n0 + wn * 64 + (lane & 15);
    #pragma unroll
    for (int i = 0; i < 2; i++) {
        #pragma unroll
        for (int j = 0; j < 4; j++) {
            int cc = cBase + j * 16;
            float bias = b2[e * D_MODEL + cc];
            #pragma unroll
            for (int rg = 0; rg < 4; rg++) {
                int rr = rBase + i * 16 + rg;
                if (rr < nE) {
                    int slot = o0 + rr;
                    float wgt = wl[slot];
                    ybuf[(size_t)slot * D_MODEL + cc] = f2bf(wgt * (acc[i][j][rg] + bias));
                }
            }
        }
    }
}

// ---------------- combine (bf16 ybuf -> fp32 out) ----------------

__global__ void k_combine(const short* __restrict__ ybuf, const int* __restrict__ slot_of,
                          float* __restrict__ out) {
    int n = blockIdx.x;
    int s0 = slot_of[n * 2], s1 = slot_of[n * 2 + 1];
    int t = threadIdx.x;
    short4 a = *(const short4*)(ybuf + (size_t)s0 * D_MODEL + t * 4);
    short4 b = *(const short4*)(ybuf + (size_t)s1 * D_MODEL + t * 4);
    float4 o;
    o.x = bf2f(a.x) + bf2f(b.x);
    o.y = bf2f(a.y) + bf2f(b.y);
    o.z = bf2f(a.z) + bf2f(b.z);
    o.w = bf2f(a.w) + bf2f(b.w);
    *(float4*)(out + (size_t)n * D_MODEL + t * 4) = o;
}

// ---------------- launch ----------------

extern "C" void kernel_launch(void* const* d_in, const int* in_sizes, int n_in,
                              void* d_out, int out_size, void* d_ws, size_t ws_size,
                              hipStream_t stream) {
    const float* x  = (const float*)d_in[0];
    const float* gw = (const float*)d_in[1];
    const float* w1 = (const float*)d_in[2];
    const float* b1 = (const float*)d_in[3];
    const float* w2 = (const float*)d_in[4];
    const float* b2 = (const float*)d_in[5];
    float* out = (float*)d_out;

    char* ws = (char*)d_ws;
    size_t off = 0;
    auto alloc = [&](size_t bytes) -> void* {
        void* p = ws + off;
        off += (bytes + 255) & ~(size_t)255;
        return p;
    };
    int*   offs    = (int*)alloc(64);
    int*   tki     = (int*)alloc((size_t)NTOK * 2 * 4);
    float* tkw     = (float*)alloc((size_t)NTOK * 2 * 4);
    int*   list    = (int*)alloc((size_t)NSLOT * 4);
    float* wl      = (float*)alloc((size_t)NSLOT * 4);
    int*   slot_of = (int*)alloc((size_t)NTOK * 2 * 4);
    short* xb      = (short*)alloc((size_t)NTOK * D_MODEL * 2);
    short* w1t     = (short*)alloc((size_t)NE * D_HID * D_MODEL * 2);
    short* w2t     = (short*)alloc((size_t)NE * D_MODEL * D_HID * 2);
    short* hbuf    = (short*)alloc((size_t)NSLOT * D_HID * 2);
    short* ybuf    = (short*)alloc((size_t)NSLOT * D_MODEL * 2);

    k_cvt_router<<<dim3(NTOK / 4), 256, 0, stream>>>(x, gw, xb, tki, tkw);
    k_transpose_cvt2<<<dim3(64, 16, 16), 256, 0, stream>>>(w1, w2, w1t, w2t);
    k_bucket<<<dim3(1), 1024, 0, stream>>>(tki, tkw, offs, list, wl, slot_of);
    k_gemm1<<<dim3(16384), 256, 0, stream>>>(xb, w1t, b1, offs, list, hbuf);
    k_gemm2<<<dim3(4096), 256, 0, stream>>>(hbuf, w2t, b2, offs, wl, ybuf);
    k_combine<<<dim3(NTOK), 256, 0, stream>>>(ybuf, slot_of, out);
}

// Round 19
// 299.689 us; speedup vs baseline: 1.0842x; 1.0642x over previous
//
#include <hip/hip_runtime.h>
#include <hip/hip_bf16.h>
#include <math.h>

#define D_MODEL 1024
#define D_HID   4096
#define NE      8
#define NTOK    4096
#define NSLOT   8192
#define NSLOTP  (NSLOT + 512)   // padded slot capacity (per-expert round-up to 64)

typedef __attribute__((ext_vector_type(8))) short s8v;
typedef __attribute__((ext_vector_type(4))) float f32x4;

__device__ __forceinline__ short f2bf(float f) {
    unsigned u = __float_as_uint(f);
    unsigned r = (u + 0x7fffu + ((u >> 16) & 1u)) >> 16;
    return (short)r;
}

__device__ __forceinline__ float bf2f(short s) {
    unsigned u = ((unsigned)(unsigned short)s) << 16;
    return __uint_as_float(u);
}

__device__ __forceinline__ void load_lds16(const short* g, short* l) {
    __builtin_amdgcn_global_load_lds(
        (const __attribute__((address_space(1))) void*)g,
        (__attribute__((address_space(3))) void*)l, 16, 0, 0);
}

// tanh-GELU (max abs err ~3e-4 — far under the bf16 floor we already carry)
__device__ __forceinline__ float gelu_t(float v) {
    float u = v * fmaf(0.0356774081f, v * v, 0.7978845608f);
    float e = __expf(-2.0f * u);
    return v * __builtin_amdgcn_rcpf(1.0f + e);
}

// ---------------- fused x-convert + router (256 thr, 1 wave per token) ----------------

__global__ __launch_bounds__(256) void k_cvt_router(
    const float* __restrict__ x, const float* __restrict__ gw,
    short* __restrict__ xb,
    int* __restrict__ tki, float* __restrict__ tkw) {
    int n = blockIdx.x * 4 + (threadIdx.x >> 6);
    int lane = threadIdx.x & 63;
    const float4* x4 = (const float4*)x;
    const float4* g4 = (const float4*)gw;
    float4 xv[4];
    #pragma unroll
    for (int j = 0; j < 4; j++) xv[j] = x4[(size_t)n * 256 + lane + 64 * j];
    #pragma unroll
    for (int j = 0; j < 4; j++) {
        short4 o;
        o.x = f2bf(xv[j].x); o.y = f2bf(xv[j].y);
        o.z = f2bf(xv[j].z); o.w = f2bf(xv[j].w);
        *(short4*)(xb + (size_t)n * D_MODEL + 4 * (lane + 64 * j)) = o;
    }
    float l[8];
    #pragma unroll
    for (int e = 0; e < 8; e++) {
        float a = 0.f;
        #pragma unroll
        for (int j = 0; j < 4; j++) {
            float4 g = g4[e * 256 + lane + 64 * j];
            a = fmaf(xv[j].x, g.x, a);
            a = fmaf(xv[j].y, g.y, a);
            a = fmaf(xv[j].z, g.z, a);
            a = fmaf(xv[j].w, g.w, a);
        }
        #pragma unroll
        for (int s = 32; s > 0; s >>= 1) a += __shfl_xor(a, s);
        l[e] = a;
    }
    if (lane == 0) {
        float bv = -1e30f, sv = -1e30f; int bi = 0, si = 0;
        #pragma unroll
        for (int e = 0; e < 8; e++) {
            float v = l[e];
            if (v > bv) { sv = bv; si = bi; bv = v; bi = e; }
            else if (v > sv) { sv = v; si = e; }
        }
        float w0 = 1.f / (1.f + expf(sv - bv));
        tki[n * 2] = bi; tki[n * 2 + 1] = si;
        tkw[n * 2] = w0; tkw[n * 2 + 1] = 1.f - w0;
    }
}

// ---------------- weight transposes (merged) ----------------

__global__ void k_transpose_cvt2(const float* __restrict__ w1, const float* __restrict__ w2,
                                 short* __restrict__ w1t, short* __restrict__ w2t) {
    __shared__ float tile[64][65];
    int z = blockIdx.z;
    int R, C;
    const float* inp;
    short* outp;
    int tIdx = blockIdx.y * 64 + blockIdx.x;
    if (z < 8) {
        R = D_MODEL; C = D_HID;
        inp  = w1  + (size_t)z * R * C;
        outp = w1t + (size_t)z * R * C;
    } else {
        R = D_HID; C = D_MODEL;
        inp  = w2  + (size_t)(z - 8) * R * C;
        outp = w2t + (size_t)(z - 8) * R * C;
    }
    int tilesC = C >> 6;
    int c0 = (tIdx % tilesC) * 64;
    int r0 = (tIdx / tilesC) * 64;
    int t = threadIdx.x;
    #pragma unroll
    for (int p = 0; p < 4; p++) {
        int idx = p * 256 + t;
        int r = idx >> 4;
        int c4 = (idx & 15) * 4;
        float4 v = *(const float4*)(inp + (size_t)(r0 + r) * C + c0 + c4);
        tile[r][c4 + 0] = v.x; tile[r][c4 + 1] = v.y;
        tile[r][c4 + 2] = v.z; tile[r][c4 + 3] = v.w;
    }
    __syncthreads();
    #pragma unroll
    for (int p = 0; p < 4; p++) {
        int idx = p * 256 + t;
        int cc = idx >> 4;
        int rg = (idx & 15) * 4;
        short4 v;
        v.x = f2bf(tile[rg + 0][cc]);
        v.y = f2bf(tile[rg + 1][cc]);
        v.z = f2bf(tile[rg + 2][cc]);
        v.w = f2bf(tile[rg + 3][cc]);
        *(short4*)(outp + (size_t)(c0 + cc) * R + r0 + rg) = v;
    }
}

// ---------------- bucketing: count + scan(pad-to-64) + zero + fill ----------------
// Per-expert counts rounded UP to 64 so every 64-row m-block lies entirely in
// one expert. Pad slots carry token 0 / weight 0 -> inert downstream (gemm2
// scales by 0; combine never reads pads).

__global__ __launch_bounds__(1024) void k_bucket(
    const int* __restrict__ tki, const float* __restrict__ tkw,
    int* __restrict__ offs,            // [9] padded offsets
    int* __restrict__ list, float* __restrict__ wl, int* __restrict__ slot_of) {
    __shared__ int cnt[NE], base[NE + 1], fil[NE];
    int t = threadIdx.x;
    if (t < NE) { cnt[t] = 0; fil[t] = 0; }
    __syncthreads();
    for (int n = t; n < NTOK; n += 1024) {
        atomicAdd(&cnt[tki[n * 2]], 1);
        atomicAdd(&cnt[tki[n * 2 + 1]], 1);
    }
    __syncthreads();
    if (t == 0) {
        int a = 0;
        for (int e = 0; e < NE; e++) { base[e] = a; a += (cnt[e] + 63) & ~63; }
        base[NE] = a;
    }
    __syncthreads();
    if (t < NE + 1) offs[t] = base[t];
    // zero the whole padded slot space (pads stay token 0 / weight 0)
    for (int p = t; p < NSLOTP; p += 1024) { list[p] = 0; wl[p] = 0.f; }
    __syncthreads();
    for (int n = t; n < NTOK; n += 1024) {
        #pragma unroll
        for (int k = 0; k < 2; k++) {
            int e = tki[n * 2 + k];
            int p = base[e] + atomicAdd(&fil[e], 1);
            list[p] = n;
            wl[p] = tkw[n * 2 + k];
            slot_of[n * 2 + k] = p;
        }
    }
}

// ---------------- shared pipeline macros ----------------

#define PIPE_WAIT(NSTR) \
    asm volatile("s_waitcnt vmcnt(" NSTR ")" ::: "memory"); \
    __builtin_amdgcn_s_barrier(); \
    __builtin_amdgcn_sched_barrier(0);

#define PIPE_POST \
    asm volatile("" ::: "memory"); \
    __builtin_amdgcn_s_barrier();

#define GEMM_PIPE_LOOP(KDIM, STAGE, COMPUTE, NSTR) \
    STAGE(As0, Bs0); \
    for (int k0 = 0; k0 < (KDIM) - 128; k0 += 128) { \
        STAGE(As1, Bs1); PIPE_WAIT(NSTR) COMPUTE(As0, Bs0) PIPE_POST \
        STAGE(As0, Bs0); PIPE_WAIT(NSTR) COMPUTE(As1, Bs1) PIPE_POST \
    } \
    STAGE(As1, Bs1); PIPE_WAIT(NSTR) COMPUTE(As0, Bs0) PIPE_POST \
    PIPE_WAIT("0") COMPUTE(As1, Bs1)

// ---------------- 64(M)x128(N) tile machinery (round-12/13-verified) ----------------

#define STAGE_T(ABASE, BBASE) \
    { _Pragma("unroll") \
      for (int c = 0; c < 2; c++) { load_lds16(aS[c], (ABASE) + ldsDa[c]); aS[c] += 64; } \
      _Pragma("unroll") \
      for (int c = 0; c < 4; c++) { load_lds16(bS[c], (BBASE) + ldsDb[c]); bS[c] += 64; } }

#define COMPUTE_T(ABASE, BBASE) \
    { _Pragma("unroll") \
      for (int kk = 0; kk < 2; kk++) { \
          s8v a[2], b[4]; \
          _Pragma("unroll") \
          for (int i = 0; i < 2; i++) a[i] = *(const s8v*)((ABASE) + aO[i][kk]); \
          _Pragma("unroll") \
          for (int j = 0; j < 4; j++) b[j] = *(const s8v*)((BBASE) + bO[j][kk]); \
          _Pragma("unroll") \
          for (int i = 0; i < 2; i++) \
              _Pragma("unroll") \
              for (int j = 0; j < 4; j++) \
                  acc[i][j] = __builtin_amdgcn_mfma_f32_16x16x32_bf16(a[i], b[j], acc[i][j], 0, 0, 0); \
      } }

#define FRAG_SETUP_T \
    int tid = threadIdx.x; \
    int lane = tid & 63; \
    int wid = tid >> 6; \
    int wm = wid >> 1, wn = wid & 1; \
    f32x4 acc[2][4] = {}; \
    int aO[2][2], bO[4][2]; \
    _Pragma("unroll") \
    for (int k = 0; k < 2; k++) { \
        int l = k * 4 + (lane >> 4); \
        _Pragma("unroll") \
        for (int i = 0; i < 2; i++) { \
            int R = wm * 32 + i * 16 + (lane & 15); \
            aO[i][k] = R * 64 + ((l ^ (R & 7)) * 8); \
        } \
        _Pragma("unroll") \
        for (int j = 0; j < 4; j++) { \
            int R = wn * 64 + j * 16 + (lane & 15); \
            bO[j][k] = R * 64 + ((l ^ (R & 7)) * 8); \
        } \
    }

// ---------------- GEMM 1: 64x128 single-buffer TLP, EXACT padded grid ----------------
// Global m-space of padded slots: 136 m-blocks x 32 n = 4352 blocks (~0% waste
// vs 75% empty at the old 16384 grid). Expert found by 8-compare lookup.
// Chunked order (8n x 8m super-chunks) preserved from round 16.

__global__ __launch_bounds__(256) void k_gemm1(
    const short* __restrict__ xb,      // [NTOK][D_MODEL] bf16
    const short* __restrict__ w1t,     // [E][D_HID][D_MODEL] bf16
    const float* __restrict__ b1,
    const int* __restrict__ offs,      // padded
    const int* __restrict__ list,
    short* __restrict__ hbuf)          // [NSLOTP][D_HID] bf16
{
    int id = blockIdx.x;               // grid 4352 = 8 * 544
    int w = (id & 7) * 544 + (id >> 3);
    int chunk = w >> 6;                // 68 chunks: 4 nb-groups x 17 mb-groups
    int intra = w & 63;
    int nb = (chunk & 3) * 8 + (intra & 7);
    int mb = (chunk >> 2) * 8 + (intra >> 3);   // 0..135
    int base = mb * 64;
    int total = offs[NE];
    if (base >= total) return;
    int e = 0;
    #pragma unroll
    for (int q = 1; q < NE; q++) e += (base >= offs[q]) ? 1 : 0;
    int o0 = offs[e];
    int m0 = base - o0;                // block fully inside expert (64-aligned)
    int n0 = nb * 128;

    __shared__ short As[64 * 64];      // 8 KB
    __shared__ short Bs[128 * 64];     // 16 KB

    int tid = threadIdx.x;
    int lane = tid & 63;
    int wid = tid >> 6;
    int wm = wid >> 1, wn = wid & 1;   // wave tile 32(M) x 64(N)

    f32x4 acc[2][4] = {};

    const short* aS[2]; const short* bS[4];
    int ldsDa[2], ldsDb[4];
    #pragma unroll
    for (int c = 0; c < 2; c++) {
        int i = c * 256 + tid;                   // 0..511
        int rowT = i >> 3, s = i & 7;
        int ch = s ^ (rowT & 7);                 // pre-swizzled source chunk
        int tok = list[base + rowT];             // pads -> token 0 (valid)
        aS[c] = xb + (size_t)tok * D_MODEL + ch * 8;
        ldsDa[c] = i * 8;
    }
    #pragma unroll
    for (int c = 0; c < 4; c++) {
        int i = c * 256 + tid;                   // 0..1023
        int rowT = i >> 3, s = i & 7;
        int ch = s ^ (rowT & 7);
        bS[c] = w1t + ((size_t)e * D_HID + n0 + rowT) * D_MODEL + ch * 8;
        ldsDb[c] = i * 8;
    }

    int aO[2][2], bO[4][2];
    #pragma unroll
    for (int k = 0; k < 2; k++) {
        int l = k * 4 + (lane >> 4);
        #pragma unroll
        for (int i = 0; i < 2; i++) {
            int R = wm * 32 + i * 16 + (lane & 15);
            aO[i][k] = R * 64 + ((l ^ (R & 7)) * 8);
        }
        #pragma unroll
        for (int j = 0; j < 4; j++) {
            int R = wn * 64 + j * 16 + (lane & 15);
            bO[j][k] = R * 64 + ((l ^ (R & 7)) * 8);
        }
    }

    for (int k0 = 0; k0 < D_MODEL; k0 += 64) {
        __syncthreads();
        #pragma unroll
        for (int c = 0; c < 2; c++) { load_lds16(aS[c], As + ldsDa[c]); aS[c] += 64; }
        #pragma unroll
        for (int c = 0; c < 4; c++) { load_lds16(bS[c], Bs + ldsDb[c]); bS[c] += 64; }
        asm volatile("s_waitcnt vmcnt(0)" ::: "memory");
        __syncthreads();
        #pragma unroll
        for (int kk = 0; kk < 2; kk++) {
            s8v a[2], b[4];
            #pragma unroll
            for (int i = 0; i < 2; i++) a[i] = *(const s8v*)(As + aO[i][kk]);
            #pragma unroll
            for (int j = 0; j < 4; j++) b[j] = *(const s8v*)(Bs + bO[j][kk]);
            #pragma unroll
            for (int i = 0; i < 2; i++)
                #pragma unroll
                for (int j = 0; j < 4; j++)
                    acc[i][j] = __builtin_amdgcn_mfma_f32_16x16x32_bf16(a[i], b[j], acc[i][j], 0, 0, 0);
        }
    }

    int rBase = base + wm * 32 + (lane >> 4) * 4;
    int cBase = n0 + wn * 64 + (lane & 15);
    #pragma unroll
    for (int i = 0; i < 2; i++) {
        #pragma unroll
        for (int j = 0; j < 4; j++) {
            int cc = cBase + j * 16;
            float bias = b1[e * D_HID + cc];
            #pragma unroll
            for (int rg = 0; rg < 4; rg++) {
                int rr = rBase + i * 16 + rg;
                float v = acc[i][j][rg] + bias;
                hbuf[(size_t)rr * D_HID + cc] = f2bf(gelu_t(v));
            }
        }
    }
}

// ---------------- GEMM 2: 64x128, 2-buf counted + TLP (round-13 exact, padded offs OK) ----------------

__global__ __launch_bounds__(256) void k_gemm2(
    const short* __restrict__ hbuf,    // [NSLOTP][D_HID] bf16
    const short* __restrict__ w2t,     // [E][D_MODEL][D_HID] bf16
    const float* __restrict__ b2,
    const int* __restrict__ offs,
    const float* __restrict__ wl,
    short* __restrict__ ybuf)          // [NSLOTP][D_MODEL] bf16
{
    int id = blockIdx.x;
    int w = (id & 7) * 512 + (id >> 3);
    int e = w >> 9;
    int o0 = offs[e];
    int nE = offs[e + 1] - o0;         // padded, multiple of 64
    int m0 = ((w >> 3) & 63) * 64;
    if (m0 >= nE) return;
    int n0 = (w & 7) * 128;

    __shared__ short As0[64 * 64], Bs0[128 * 64];
    __shared__ short As1[64 * 64], Bs1[128 * 64];

    FRAG_SETUP_T

    const short* aS[2]; const short* bS[4];
    int ldsDa[2], ldsDb[4];
    #pragma unroll
    for (int c = 0; c < 2; c++) {
        int i = c * 256 + tid;
        int rowT = i >> 3, s = i & 7;
        int ch = s ^ (rowT & 7);
        aS[c] = hbuf + (size_t)(o0 + m0 + rowT) * D_HID + ch * 8;
        ldsDa[c] = i * 8;
    }
    #pragma unroll
    for (int c = 0; c < 4; c++) {
        int i = c * 256 + tid;
        int rowT = i >> 3, s = i & 7;
        int ch = s ^ (rowT & 7);
        bS[c] = w2t + ((size_t)e * D_MODEL + n0 + rowT) * D_HID + ch * 8;
        ldsDb[c] = i * 8;
    }

    GEMM_PIPE_LOOP(D_HID, STAGE_T, COMPUTE_T, "6")

    int rBase = m0 + wm * 32 + (lane >> 4) * 4;
    int cBase = n0 + wn * 64 + (lane & 15);
    #pragma unroll
    for (int i = 0; i < 2; i++) {
        #pragma unroll
        for (int j = 0; j < 4; j++) {
            int cc = cBase + j * 16;
            float bias = b2[e * D_MODEL + cc];
            #pragma unroll
            for (int rg = 0; rg < 4; rg++) {
                int rr = rBase + i * 16 + rg;
                int slot = o0 + rr;
                float wgt = wl[slot];          // pads: 0
                ybuf[(size_t)slot * D_MODEL + cc] = f2bf(wgt * (acc[i][j][rg] + bias));
            }
        }
    }
}

// ---------------- combine (bf16 ybuf -> fp32 out) ----------------

__global__ void k_combine(const short* __restrict__ ybuf, const int* __restrict__ slot_of,
                          float* __restrict__ out) {
    int n = blockIdx.x;
    int s0 = slot_of[n * 2], s1 = slot_of[n * 2 + 1];
    int t = threadIdx.x;
    short4 a = *(const short4*)(ybuf + (size_t)s0 * D_MODEL + t * 4);
    short4 b = *(const short4*)(ybuf + (size_t)s1 * D_MODEL + t * 4);
    float4 o;
    o.x = bf2f(a.x) + bf2f(b.x);
    o.y = bf2f(a.y) + bf2f(b.y);
    o.z = bf2f(a.z) + bf2f(b.z);
    o.w = bf2f(a.w) + bf2f(b.w);
    *(float4*)(out + (size_t)n * D_MODEL + t * 4) = o;
}

// ---------------- launch ----------------

extern "C" void kernel_launch(void* const* d_in, const int* in_sizes, int n_in,
                              void* d_out, int out_size, void* d_ws, size_t ws_size,
                              hipStream_t stream) {
    const float* x  = (const float*)d_in[0];
    const float* gw = (const float*)d_in[1];
    const float* w1 = (const float*)d_in[2];
    const float* b1 = (const float*)d_in[3];
    const float* w2 = (const float*)d_in[4];
    const float* b2 = (const float*)d_in[5];
    float* out = (float*)d_out;

    char* ws = (char*)d_ws;
    size_t off = 0;
    auto alloc = [&](size_t bytes) -> void* {
        void* p = ws + off;
        off += (bytes + 255) & ~(size_t)255;
        return p;
    };
    int*   offs    = (int*)alloc(64);
    int*   tki     = (int*)alloc((size_t)NTOK * 2 * 4);
    float* tkw     = (float*)alloc((size_t)NTOK * 2 * 4);
    int*   list    = (int*)alloc((size_t)NSLOTP * 4);
    float* wl      = (float*)alloc((size_t)NSLOTP * 4);
    int*   slot_of = (int*)alloc((size_t)NTOK * 2 * 4);
    short* xb      = (short*)alloc((size_t)NTOK * D_MODEL * 2);
    short* w1t     = (short*)alloc((size_t)NE * D_HID * D_MODEL * 2);
    short* w2t     = (short*)alloc((size_t)NE * D_MODEL * D_HID * 2);
    short* hbuf    = (short*)alloc((size_t)NSLOTP * D_HID * 2);
    short* ybuf    = (short*)alloc((size_t)NSLOTP * D_MODEL * 2);

    k_cvt_router<<<dim3(NTOK / 4), 256, 0, stream>>>(x, gw, xb, tki, tkw);
    k_transpose_cvt2<<<dim3(64, 16, 16), 256, 0, stream>>>(w1, w2, w1t, w2t);
    k_bucket<<<dim3(1), 1024, 0, stream>>>(tki, tkw, offs, list, wl, slot_of);
    k_gemm1<<<dim3(4352), 256, 0, stream>>>(xb, w1t, b1, offs, list, hbuf);
    k_gemm2<<<dim3(4096), 256, 0, stream>>>(hbuf, w2t, b2, offs, wl, ybuf);
    k_combine<<<dim3(NTOK), 256, 0, stream>>>(ybuf, slot_of, out);
}